// Round 6
// baseline (220.194 us; speedup 1.0000x reference)
//
#include <hip/hip_runtime.h>

#define SEQ 2048
#define NH 16
#define HD 64
#define DMODEL 1024

__device__ __forceinline__ unsigned int f2bf(float f) {
  // fp32 -> bf16 bits, round-to-nearest-even (finite inputs only)
  unsigned int u = __float_as_uint(f);
  return ((u + 0x7fffu + ((u >> 16) & 1u)) >> 16) & 0xffffu;
}

// packed fp32x2 -> bf16x2 (RNE via __bf16 cvt)
__device__ __forceinline__ unsigned int pk2bf(float a, float b) {
  unsigned short ua = __builtin_bit_cast(unsigned short, (__bf16)a);
  unsigned short ub = __builtin_bit_cast(unsigned short, (__bf16)b);
  return (unsigned int)ua | ((unsigned int)ub << 16);
}

typedef __bf16 bf16x8 __attribute__((ext_vector_type(8)));
typedef float f32x4 __attribute__((ext_vector_type(4)));

// async global->LDS, 16B per lane; LDS dest = wave-uniform base + lane*16
__device__ __forceinline__ void gl2lds16(const unsigned short* g, unsigned short* l) {
  __builtin_amdgcn_global_load_lds(
      (const __attribute__((address_space(1))) unsigned int*)g,
      (__attribute__((address_space(3))) unsigned int*)l, 16, 0, 0);
}

// one launch casts x + all four weight matrices to bf16
__global__ __launch_bounds__(256) void cast_all_kernel(
    const float* __restrict__ x, const float* __restrict__ wq,
    const float* __restrict__ wk, const float* __restrict__ wv,
    const float* __restrict__ wo,
    unsigned short* __restrict__ xb, unsigned short* __restrict__ wqb,
    unsigned short* __restrict__ wkb, unsigned short* __restrict__ wvb,
    unsigned short* __restrict__ wob) {
  int idx = blockIdx.x * 256 + threadIdx.x;
  if (idx >= 1048576) return;
  const float* src;
  unsigned short* dst;
  int off;
  if (idx < 524288) {
    src = x; dst = xb; off = idx;
  } else {
    int t = idx - 524288;
    int w = t >> 17;
    off = t & 131071;
    src = (w == 0) ? wq : (w == 1) ? wk : (w == 2) ? wv : wo;
    dst = (w == 0) ? wqb : (w == 1) ? wkb : (w == 2) ? wvb : wob;
  }
  const float4* p = reinterpret_cast<const float4*>(src) + (size_t)off * 2;
  float4 a = p[0], b = p[1];
  uint4 o;
  o.x = f2bf(a.x) | (f2bf(a.y) << 16);
  o.y = f2bf(a.z) | (f2bf(a.w) << 16);
  o.z = f2bf(b.x) | (f2bf(b.y) << 16);
  o.w = f2bf(b.z) | (f2bf(b.w) << 16);
  reinterpret_cast<uint4*>(dst)[off] = o;
}

// 128x128-tile GEMM, BK=64, global_load_lds staging, XOR-swizzled LDS chunks.
// MODE 0: fused QKV epilogue (cols 0..1023 Q *qscale, 1024..2047 K, 2048..3071 V^T).
// MODE 1: fp32 C[M][1024] + bias0 (out projection).
template <int MODE>
__global__ __launch_bounds__(256) void gemm128(
    const unsigned short* __restrict__ A, const unsigned short* __restrict__ B,
    const float* __restrict__ bias0, const float* __restrict__ bias1,
    const float* __restrict__ bias2, float* __restrict__ Cf,
    unsigned short* __restrict__ Qo, unsigned short* __restrict__ Ko,
    unsigned short* __restrict__ Vto, int Kdim) {
  __shared__ __align__(16) unsigned short As[128 * 64];
  __shared__ __align__(16) unsigned short Bs[128 * 64];
  const int tid = threadIdx.x;
  const int wave = tid >> 6, lane = tid & 63;
  const int wm = wave >> 1, wn = wave & 1;  // 2x2 waves -> 64x64 sub-tiles
  const int fr = lane & 15, quad = lane >> 4;
  const int fx = fr & 7;  // swizzle key for fragment reads
  const int n0 = blockIdx.x * 128, m0 = blockIdx.y * 128;

  // staging: lane -> (row = lane>>3, swizzled chunk = (lane&7) ^ ((lane>>3)&7))
  const int srowg = lane >> 3;
  const int schunk = (lane & 7) ^ (srowg & 7);
  const unsigned short* Abase =
      A + (size_t)(m0 + wave * 32 + srowg) * Kdim + schunk * 8;
  const unsigned short* Bbase =
      B + (size_t)(n0 + wave * 32 + srowg) * Kdim + schunk * 8;
  unsigned short* AsW = As + (wave * 32) * 64;
  unsigned short* BsW = Bs + (wave * 32) * 64;

  f32x4 acc[4][4];
#pragma unroll
  for (int mt = 0; mt < 4; ++mt)
#pragma unroll
    for (int nt = 0; nt < 4; ++nt) acc[mt][nt] = f32x4{0.f, 0.f, 0.f, 0.f};

  for (int k0 = 0; k0 < Kdim; k0 += 64) {
#pragma unroll
    for (int t = 0; t < 4; ++t) {
      gl2lds16(Abase + (size_t)(t * 8) * Kdim + k0, AsW + t * 8 * 64);
      gl2lds16(Bbase + (size_t)(t * 8) * Kdim + k0, BsW + t * 8 * 64);
    }
    __syncthreads();  // drains vmcnt(0): staged tile visible
#pragma unroll
    for (int ks = 0; ks < 2; ++ks) {
      bf16x8 af[4], bfv[4];
#pragma unroll
      for (int mt = 0; mt < 4; ++mt)
        af[mt] = *reinterpret_cast<const bf16x8*>(
            As + (wm * 64 + mt * 16 + fr) * 64 + ((ks * 4 + quad) ^ fx) * 8);
#pragma unroll
      for (int nt = 0; nt < 4; ++nt)
        bfv[nt] = *reinterpret_cast<const bf16x8*>(
            Bs + (wn * 64 + nt * 16 + fr) * 64 + ((ks * 4 + quad) ^ fx) * 8);
#pragma unroll
      for (int mt = 0; mt < 4; ++mt)
#pragma unroll
        for (int nt = 0; nt < 4; ++nt)
          acc[mt][nt] = __builtin_amdgcn_mfma_f32_16x16x32_bf16(
              af[mt], bfv[nt], acc[mt][nt], 0, 0, 0);
    }
    __syncthreads();
  }

  // epilogue. C/D: col = lane&15, row = quad*4+reg (m89/m91-verified).
  if (MODE == 0) {
    const int seg = n0 >> 10;  // uniform per block
    const float* bp = (seg == 0) ? bias0 : (seg == 1) ? bias1 : bias2;
    // Q pre-scaled by (1/sqrt(64)) * log2(e): attention works in exp2 domain
    const float scale = (seg == 0) ? 0.1803368809f : 1.0f;
    unsigned short* QK = (seg == 0) ? Qo : Ko;
#pragma unroll
    for (int nt = 0; nt < 4; ++nt) {
      const int c = (n0 + wn * 64 + nt * 16 + fr) & 1023;
      const int h = c >> 6, d = c & 63;
      const float bs = bp[c];
#pragma unroll
      for (int mt = 0; mt < 4; ++mt) {
        const int mbase = m0 + wm * 64 + mt * 16 + quad * 4;
        const int b = mbase >> 11, s0 = mbase & 2047;
        if (seg < 2) {
          unsigned short* dst = QK + (((size_t)(b * NH + h)) * SEQ + s0) * HD + d;
#pragma unroll
          for (int r = 0; r < 4; ++r)
            dst[(size_t)r * HD] = (unsigned short)f2bf((acc[mt][nt][r] + bs) * scale);
        } else {  // V^T: rows contiguous in s -> 8B store
          uint2 pk;
          pk.x = pk2bf(acc[mt][nt][0] + bs, acc[mt][nt][1] + bs);
          pk.y = pk2bf(acc[mt][nt][2] + bs, acc[mt][nt][3] + bs);
          *reinterpret_cast<uint2*>(
              Vto + (((size_t)(b * NH + h)) * HD + d) * SEQ + s0) = pk;
        }
      }
    }
  } else {
#pragma unroll
    for (int nt = 0; nt < 4; ++nt) {
      const int cg = n0 + wn * 64 + nt * 16 + fr;
      const float bs = bias0[cg];
#pragma unroll
      for (int mt = 0; mt < 4; ++mt) {
        const int mbase = m0 + wm * 64 + mt * 16 + quad * 4;
#pragma unroll
        for (int r = 0; r < 4; ++r)
          Cf[(size_t)(mbase + r) * DMODEL + cg] = acc[mt][nt][r] + bs;
      }
    }
  }
}

// MFMA flash attention, exp2 domain, BARRIER-FREE.
// Block (g,bh), g in [0,8): 4 waves; each wave serves rows [wave*16,wave*16+16)
// of FOUR i-tiles {g, 15-g, 16+g, 31-g} (66 tile-passes per block, exact balance).
// K/V fragments are read directly from global (L2/L3-resident; frag layout is
// identical to what LDS staging held) -> no shared staging, no __syncthreads.
// Pt (P C-layout -> A-layout round-trip) is wave-private LDS, lgkmcnt-ordered.
// S^T = K*Q^T then O^T = V^T*P^T keeps each lane's C-col = its own Q row.
__global__ __launch_bounds__(256) void attn_mfma_kernel(
    const unsigned short* __restrict__ Qg, const unsigned short* __restrict__ Kg,
    const unsigned short* __restrict__ Vtg, const int* __restrict__ mask,
    unsigned short* __restrict__ concat) {
  const int g = blockIdx.x >> 5;        // 0..7
  const int bh = blockIdx.x & 31;
  const int b = bh >> 4, h = bh & 15;
  const int tid = threadIdx.x;
  const int wave = tid >> 6, lane = tid & 63;
  const int quad = lane >> 4, fr = lane & 15;
  const int ib[4] = {g, 15 - g, 16 + g, 31 - g};  // ascending

  __shared__ unsigned short Pt[4][4][16][72];  // [wave][tile][i][j], wave-private

  const unsigned short* Qb = Qg + ((size_t)bh * SEQ) * HD;
  const unsigned short* Kb = Kg + ((size_t)bh * SEQ) * HD;
  const unsigned short* Vtb = Vtg + ((size_t)bh * HD) * SEQ;
  const int* maskb = mask + b * SEQ;

  // pad-mask tile bitmap, wave-local: lane covers mask ints [lane*32, lane*32+32)
  // -> tile jc is covered by ballot bits {2jc, 2jc+1}
  bool bad = false;
  {
    const int4* mp4 = reinterpret_cast<const int4*>(maskb);
#pragma unroll
    for (int u = 0; u < 8; ++u) {
      int4 v = mp4[lane * 8 + u];
      bad |= !(v.x && v.y && v.z && v.w);
    }
  }
  const unsigned long long bm = __ballot(bad);

  int irow[4], padr[4];
  bf16x8 q0[4], q1[4];
  f32x4 o[4][4];
  float mr[4], lr[4];
#pragma unroll
  for (int t = 0; t < 4; ++t) {
    irow[t] = ib[t] * 64 + wave * 16 + fr;
    q0[t] = *reinterpret_cast<const bf16x8*>(Qb + (size_t)irow[t] * HD + quad * 8);
    q1[t] = *reinterpret_cast<const bf16x8*>(Qb + (size_t)irow[t] * HD + quad * 8 + 32);
    padr[t] = maskb[irow[t]];
    // init -1e20: all-masked tiles give exp2(-1e30+1e20)=0 safely
    mr[t] = -1e20f; lr[t] = 0.f;
#pragma unroll
    for (int vt = 0; vt < 4; ++vt) o[t][vt] = f32x4{0.f, 0.f, 0.f, 0.f};
  }

  const int jcmax = ib[3];
  for (int jc = 0; jc <= jcmax; ++jc) {
    const int j0 = jc * 64;
    // K fragments (A-operand of S^T): row j0+jt*16+fr, head-dim chunk quad*8(+32)
    bf16x8 ka0[4], ka1[4], vb0[4], vb1[4];
#pragma unroll
    for (int jt = 0; jt < 4; ++jt) {
      const unsigned short* kr = Kb + (size_t)(j0 + jt * 16 + fr) * HD + quad * 8;
      ka0[jt] = *reinterpret_cast<const bf16x8*>(kr);
      ka1[jt] = *reinterpret_cast<const bf16x8*>(kr + 32);
    }
    // V^T fragments (A-operand of PV): row vt*16+fr, j chunk j0+quad*8(+32)
#pragma unroll
    for (int vt = 0; vt < 4; ++vt) {
      const unsigned short* vr = Vtb + (size_t)(vt * 16 + fr) * SEQ + j0 + quad * 8;
      vb0[vt] = *reinterpret_cast<const bf16x8*>(vr);
      vb1[vt] = *reinterpret_cast<const bf16x8*>(vr + 32);
    }
    const bool tb = ((bm >> (2 * jc)) & 3ull) != 0ull;

#pragma unroll
    for (int t = 0; t < 4; ++t) {
      if (jc > ib[t]) continue;  // wave-uniform
      const int ir = irow[t];

      // S^T strip: C[m=j][n=i=fr]
      f32x4 st[4];
#pragma unroll
      for (int jt = 0; jt < 4; ++jt) {
        st[jt] = f32x4{0.f, 0.f, 0.f, 0.f};
        st[jt] = __builtin_amdgcn_mfma_f32_16x16x32_bf16(ka0[jt], q0[t], st[jt], 0, 0, 0);
        st[jt] = __builtin_amdgcn_mfma_f32_16x16x32_bf16(ka1[jt], q1[t], st[jt], 0, 0, 0);
      }

      if (tb) {  // rare: per-element pad-col mask
        const int4* mp = reinterpret_cast<const int4*>(maskb + j0);
#pragma unroll
        for (int jt = 0; jt < 4; ++jt) {
          const int4 mv = mp[jt * 4 + quad];
          if (mv.x == 0) st[jt][0] = -1e30f;
          if (mv.y == 0) st[jt][1] = -1e30f;
          if (mv.z == 0) st[jt][2] = -1e30f;
          if (mv.w == 0) st[jt][3] = -1e30f;
        }
      }
      if (jc == ib[t]) {  // diagonal tile: causal mask
#pragma unroll
        for (int jt = 0; jt < 4; ++jt) {
          const int jb = j0 + jt * 16 + quad * 4;
#pragma unroll
          for (int r = 0; r < 4; ++r)
            if (jb + r > ir) st[jt][r] = -1e30f;
        }
      }

      // online softmax for row i=fr (state replicated across quads)
      float tmax = -1e30f;
#pragma unroll
      for (int jt = 0; jt < 4; ++jt)
#pragma unroll
        for (int r = 0; r < 4; ++r) tmax = fmaxf(tmax, st[jt][r]);
      tmax = fmaxf(tmax, __shfl_xor(tmax, 16));
      tmax = fmaxf(tmax, __shfl_xor(tmax, 32));
      const bool upd = __ballot(tmax > mr[t]) != 0ull;  // wave-uniform
      float corr = 1.f;
      if (upd) {
        const float mn = fmaxf(mr[t], tmax);
        corr = __builtin_amdgcn_exp2f(mr[t] - mn);
        mr[t] = mn;
      }
      const float mcur = mr[t];
      float lloc = 0.f;
#pragma unroll
      for (int jt = 0; jt < 4; ++jt) {
        float p0 = __builtin_amdgcn_exp2f(st[jt][0] - mcur);
        float p1 = __builtin_amdgcn_exp2f(st[jt][1] - mcur);
        float p2 = __builtin_amdgcn_exp2f(st[jt][2] - mcur);
        float p3 = __builtin_amdgcn_exp2f(st[jt][3] - mcur);
        lloc += (p0 + p1) + (p2 + p3);
        uint2 pk; pk.x = pk2bf(p0, p1); pk.y = pk2bf(p2, p3);
        *reinterpret_cast<uint2*>(&Pt[wave][t][fr][jt * 16 + quad * 4]) = pk;
      }
      lloc += __shfl_xor(lloc, 16);
      lloc += __shfl_xor(lloc, 32);
      if (upd) {
        lr[t] = lr[t] * corr + lloc;
#pragma unroll
        for (int vt = 0; vt < 4; ++vt) {
          o[t][vt][0] *= corr; o[t][vt][1] *= corr;
          o[t][vt][2] *= corr; o[t][vt][3] *= corr;
        }
      } else {
        lr[t] += lloc;
      }

      // P round-trip (C-layout -> A-layout), wave-private, lgkmcnt-ordered
      bf16x8 pa0 = *reinterpret_cast<const bf16x8*>(&Pt[wave][t][fr][quad * 8]);
      bf16x8 pa1 = *reinterpret_cast<const bf16x8*>(&Pt[wave][t][fr][quad * 8 + 32]);
#pragma unroll
      for (int vt = 0; vt < 4; ++vt) {
        o[t][vt] = __builtin_amdgcn_mfma_f32_16x16x32_bf16(vb0[vt], pa0, o[t][vt], 0, 0, 0);
        o[t][vt] = __builtin_amdgcn_mfma_f32_16x16x32_bf16(vb1[vt], pa1, o[t][vt], 0, 0, 0);
      }
    }
  }

  // epilogue: O^T[v][i=fr] / l_i -> concat bf16 [b,s,h*64]
#pragma unroll
  for (int t = 0; t < 4; ++t) {
    const float inv = (padr[t] != 0 && lr[t] > 0.f) ? 1.f / lr[t] : 0.f;
    unsigned short* orow = concat + ((size_t)(b * SEQ + irow[t])) * DMODEL + h * HD;
#pragma unroll
    for (int vt = 0; vt < 4; ++vt) {
      uint2 pk;
      pk.x = pk2bf(o[t][vt][0] * inv, o[t][vt][1] * inv);
      pk.y = pk2bf(o[t][vt][2] * inv, o[t][vt][3] * inv);
      *reinterpret_cast<uint2*>(orow + vt * 16 + quad * 4) = pk;
    }
  }
}

extern "C" void kernel_launch(void* const* d_in, const int* in_sizes, int n_in,
                              void* d_out, int out_size, void* d_ws, size_t ws_size,
                              hipStream_t stream) {
  (void)in_sizes; (void)n_in; (void)out_size;
  const float* x  = (const float*)d_in[0];
  const int* mask = (const int*)d_in[1];
  const float* Wq = (const float*)d_in[2];
  const float* bq = (const float*)d_in[3];
  const float* Wk = (const float*)d_in[4];
  const float* bk = (const float*)d_in[5];
  const float* Wv = (const float*)d_in[6];
  const float* bv = (const float*)d_in[7];
  const float* Wo = (const float*)d_in[8];
  const float* bo = (const float*)d_in[9];
  float* out = (float*)d_out;

  char* ws = (char*)d_ws;
  if (ws_size < (48ull << 20)) return;
  unsigned short* xb  = (unsigned short*)(ws);                 // 8 MB x bf16 [4096][1024]
  unsigned short* wqb = (unsigned short*)(ws + (8ull  << 20)); // wq|wk|wv contiguous ->
  unsigned short* wkb = (unsigned short*)(ws + (10ull << 20)); //   [3072][1024] B matrix
  unsigned short* wvb = (unsigned short*)(ws + (12ull << 20));
  unsigned short* wob = (unsigned short*)(ws + (14ull << 20));
  unsigned short* Qb  = (unsigned short*)(ws + (16ull << 20)); // 8 MB [b,h,s,64] (xscale)
  unsigned short* Kb  = (unsigned short*)(ws + (24ull << 20)); // 8 MB [b,h,s,64]
  unsigned short* Vtb = (unsigned short*)(ws + (32ull << 20)); // 8 MB [b,h,64,s]
  unsigned short* cb  = (unsigned short*)(ws + (40ull << 20)); // 8 MB concat bf16

  cast_all_kernel<<<4096, 256, 0, stream>>>(x, Wq, Wk, Wv, Wo, xb, wqb, wkb, wvb, wob);

  // fused QKV projection: B = [wq; wk; wv] = [3072][1024]
  gemm128<0><<<dim3(24, 32), 256, 0, stream>>>(xb, wqb, bq, bk, bv,
                                               nullptr, Qb, Kb, Vtb, 1024);

  attn_mfma_kernel<<<256, 256, 0, stream>>>(Qb, Kb, Vtb, mask, cb);

  gemm128<1><<<dim3(8, 32), 256, 0, stream>>>(cb, wob, bo, nullptr, nullptr,
                                              out, nullptr, nullptr, nullptr, 1024);
}

// Round 7
// 201.877 us; speedup vs baseline: 1.0907x; 1.0907x over previous
//
#include <hip/hip_runtime.h>

#define SEQ 2048
#define NH 16
#define HD 64
#define DMODEL 1024

__device__ __forceinline__ unsigned int f2bf(float f) {
  // fp32 -> bf16 bits, round-to-nearest-even (finite inputs only)
  unsigned int u = __float_as_uint(f);
  return ((u + 0x7fffu + ((u >> 16) & 1u)) >> 16) & 0xffffu;
}

// packed fp32x2 -> bf16x2 (RNE via __bf16 cvt)
__device__ __forceinline__ unsigned int pk2bf(float a, float b) {
  unsigned short ua = __builtin_bit_cast(unsigned short, (__bf16)a);
  unsigned short ub = __builtin_bit_cast(unsigned short, (__bf16)b);
  return (unsigned int)ua | ((unsigned int)ub << 16);
}

typedef __bf16 bf16x8 __attribute__((ext_vector_type(8)));
typedef float f32x4 __attribute__((ext_vector_type(4)));

// async global->LDS, 16B per lane; LDS dest = wave-uniform base + lane*16
__device__ __forceinline__ void gl2lds16(const unsigned short* g, unsigned short* l) {
  __builtin_amdgcn_global_load_lds(
      (const __attribute__((address_space(1))) unsigned int*)g,
      (__attribute__((address_space(3))) unsigned int*)l, 16, 0, 0);
}

// one launch casts x + all four weight matrices to bf16
__global__ __launch_bounds__(256) void cast_all_kernel(
    const float* __restrict__ x, const float* __restrict__ wq,
    const float* __restrict__ wk, const float* __restrict__ wv,
    const float* __restrict__ wo,
    unsigned short* __restrict__ xb, unsigned short* __restrict__ wqb,
    unsigned short* __restrict__ wkb, unsigned short* __restrict__ wvb,
    unsigned short* __restrict__ wob) {
  int idx = blockIdx.x * 256 + threadIdx.x;
  if (idx >= 1048576) return;
  const float* src;
  unsigned short* dst;
  int off;
  if (idx < 524288) {
    src = x; dst = xb; off = idx;
  } else {
    int t = idx - 524288;
    int w = t >> 17;
    off = t & 131071;
    src = (w == 0) ? wq : (w == 1) ? wk : (w == 2) ? wv : wo;
    dst = (w == 0) ? wqb : (w == 1) ? wkb : (w == 2) ? wvb : wob;
  }
  const float4* p = reinterpret_cast<const float4*>(src) + (size_t)off * 2;
  float4 a = p[0], b = p[1];
  uint4 o;
  o.x = f2bf(a.x) | (f2bf(a.y) << 16);
  o.y = f2bf(a.z) | (f2bf(a.w) << 16);
  o.z = f2bf(b.x) | (f2bf(b.y) << 16);
  o.w = f2bf(b.z) | (f2bf(b.w) << 16);
  reinterpret_cast<uint4*>(dst)[off] = o;
}

// 128x128-tile GEMM, BK=64, global_load_lds staging, XOR-swizzled LDS chunks.
// MODE 0: fused QKV epilogue (cols 0..1023 Q *qscale, 1024..2047 K, 2048..3071 V^T).
// MODE 1: fp32 C[M][1024] + bias0 (out projection).
template <int MODE>
__global__ __launch_bounds__(256) void gemm128(
    const unsigned short* __restrict__ A, const unsigned short* __restrict__ B,
    const float* __restrict__ bias0, const float* __restrict__ bias1,
    const float* __restrict__ bias2, float* __restrict__ Cf,
    unsigned short* __restrict__ Qo, unsigned short* __restrict__ Ko,
    unsigned short* __restrict__ Vto, int Kdim) {
  __shared__ __align__(16) unsigned short As[128 * 64];
  __shared__ __align__(16) unsigned short Bs[128 * 64];
  const int tid = threadIdx.x;
  const int wave = tid >> 6, lane = tid & 63;
  const int wm = wave >> 1, wn = wave & 1;  // 2x2 waves -> 64x64 sub-tiles
  const int fr = lane & 15, quad = lane >> 4;
  const int fx = fr & 7;  // swizzle key for fragment reads
  const int n0 = blockIdx.x * 128, m0 = blockIdx.y * 128;

  // staging: lane -> (row = lane>>3, swizzled chunk = (lane&7) ^ ((lane>>3)&7))
  const int srowg = lane >> 3;
  const int schunk = (lane & 7) ^ (srowg & 7);
  const unsigned short* Abase =
      A + (size_t)(m0 + wave * 32 + srowg) * Kdim + schunk * 8;
  const unsigned short* Bbase =
      B + (size_t)(n0 + wave * 32 + srowg) * Kdim + schunk * 8;
  unsigned short* AsW = As + (wave * 32) * 64;
  unsigned short* BsW = Bs + (wave * 32) * 64;

  f32x4 acc[4][4];
#pragma unroll
  for (int mt = 0; mt < 4; ++mt)
#pragma unroll
    for (int nt = 0; nt < 4; ++nt) acc[mt][nt] = f32x4{0.f, 0.f, 0.f, 0.f};

  for (int k0 = 0; k0 < Kdim; k0 += 64) {
#pragma unroll
    for (int t = 0; t < 4; ++t) {
      gl2lds16(Abase + (size_t)(t * 8) * Kdim + k0, AsW + t * 8 * 64);
      gl2lds16(Bbase + (size_t)(t * 8) * Kdim + k0, BsW + t * 8 * 64);
    }
    __syncthreads();  // drains vmcnt(0): staged tile visible
#pragma unroll
    for (int ks = 0; ks < 2; ++ks) {
      bf16x8 af[4], bfv[4];
#pragma unroll
      for (int mt = 0; mt < 4; ++mt)
        af[mt] = *reinterpret_cast<const bf16x8*>(
            As + (wm * 64 + mt * 16 + fr) * 64 + ((ks * 4 + quad) ^ fx) * 8);
#pragma unroll
      for (int nt = 0; nt < 4; ++nt)
        bfv[nt] = *reinterpret_cast<const bf16x8*>(
            Bs + (wn * 64 + nt * 16 + fr) * 64 + ((ks * 4 + quad) ^ fx) * 8);
#pragma unroll
      for (int mt = 0; mt < 4; ++mt)
#pragma unroll
        for (int nt = 0; nt < 4; ++nt)
          acc[mt][nt] = __builtin_amdgcn_mfma_f32_16x16x32_bf16(
              af[mt], bfv[nt], acc[mt][nt], 0, 0, 0);
    }
    __syncthreads();
  }

  // epilogue. C/D: col = lane&15, row = quad*4+reg (m89/m91-verified).
  if (MODE == 0) {
    const int seg = n0 >> 10;  // uniform per block
    const float* bp = (seg == 0) ? bias0 : (seg == 1) ? bias1 : bias2;
    // Q pre-scaled by (1/sqrt(64)) * log2(e): attention works in exp2 domain
    const float scale = (seg == 0) ? 0.1803368809f : 1.0f;
    unsigned short* QK = (seg == 0) ? Qo : Ko;
#pragma unroll
    for (int nt = 0; nt < 4; ++nt) {
      const int c = (n0 + wn * 64 + nt * 16 + fr) & 1023;
      const int h = c >> 6, d = c & 63;
      const float bs = bp[c];
#pragma unroll
      for (int mt = 0; mt < 4; ++mt) {
        const int mbase = m0 + wm * 64 + mt * 16 + quad * 4;
        const int b = mbase >> 11, s0 = mbase & 2047;
        if (seg < 2) {
          unsigned short* dst = QK + (((size_t)(b * NH + h)) * SEQ + s0) * HD + d;
#pragma unroll
          for (int r = 0; r < 4; ++r)
            dst[(size_t)r * HD] = (unsigned short)f2bf((acc[mt][nt][r] + bs) * scale);
        } else {  // V^T: rows contiguous in s -> 8B store
          uint2 pk;
          pk.x = pk2bf(acc[mt][nt][0] + bs, acc[mt][nt][1] + bs);
          pk.y = pk2bf(acc[mt][nt][2] + bs, acc[mt][nt][3] + bs);
          *reinterpret_cast<uint2*>(
              Vto + (((size_t)(b * NH + h)) * HD + d) * SEQ + s0) = pk;
        }
      }
    }
  } else {
#pragma unroll
    for (int nt = 0; nt < 4; ++nt) {
      const int cg = n0 + wn * 64 + nt * 16 + fr;
      const float bs = bias0[cg];
#pragma unroll
      for (int mt = 0; mt < 4; ++mt) {
        const int mbase = m0 + wm * 64 + mt * 16 + quad * 4;
#pragma unroll
        for (int r = 0; r < 4; ++r)
          Cf[(size_t)(mbase + r) * DMODEL + cg] = acc[mt][nt][r] + bs;
      }
    }
  }
}

// MFMA flash attention, exp2 domain. R5 pairing + async swizzled staging +
// 2-wave blocks. Grid 1024 = (g in [0,16), sub in {0,1}) x 32 bh.
// Block handles rows [sub*32, sub*32+32) (as two 16-row wave strips) of BOTH
// tiles A=31-g and B=g in ONE j-loop (K/V staged once per iter, shared).
// Staging is global_load_lds (async DMA) into XOR-swizzled LDS (pitch 64):
// LDS[r][c] = G[r][c^(r&7)]; frag reads use chunk c^(fr&7) -> conflict-free.
// S^T = K*Q^T then O^T = V^T*P^T: lane's C-col is its own Q row.
__global__ __launch_bounds__(128) void attn_mfma_kernel(
    const unsigned short* __restrict__ Qg, const unsigned short* __restrict__ Kg,
    const unsigned short* __restrict__ Vtg, const int* __restrict__ mask,
    unsigned short* __restrict__ concat) {
  const int gs = blockIdx.x >> 5;       // 0..31 (g ascending -> heavy blocks first)
  const int g = gs >> 1, sub = gs & 1;
  const int bh = blockIdx.x & 31;
  const int b = bh >> 4, h = bh & 15;
  const int tid = threadIdx.x;
  const int wave = tid >> 6, lane = tid & 63;
  const int quad = lane >> 4, fr = lane & 15;
  const int strip = sub * 2 + wave;     // 16-row strip index 0..3 within 64-row tile
  const int ibA = 31 - g, ibB = g;

  __shared__ __align__(16) unsigned short Ks[64 * 64];   // swizzled, pitch 64
  __shared__ __align__(16) unsigned short Vts[64 * 64];  // swizzled, pitch 64
  __shared__ unsigned short Pt[2][2][16][72];            // [wave][tile], pitch 72

  const unsigned short* Qb = Qg + ((size_t)bh * SEQ) * HD;
  const unsigned short* Kb = Kg + ((size_t)bh * SEQ) * HD;
  const unsigned short* Vtb = Vtg + ((size_t)bh * HD) * SEQ;
  const int* maskb = mask + b * SEQ;

  // pad-mask tile bitmap via wave ballot: lane covers ints [lane*32, lane*32+32)
  // -> tile jc covered by ballot bits {2jc, 2jc+1}
  bool badl = false;
  {
    const int4* mp4 = reinterpret_cast<const int4*>(maskb);
#pragma unroll
    for (int u = 0; u < 8; ++u) {
      int4 v = mp4[lane * 8 + u];
      badl |= !(v.x && v.y && v.z && v.w);
    }
  }
  const unsigned long long bm = __ballot(badl);

  const int irA = ibA * 64 + strip * 16 + fr;
  const int irB = ibB * 64 + strip * 16 + fr;
  const bf16x8 qA0 = *reinterpret_cast<const bf16x8*>(Qb + (size_t)irA * HD + quad * 8);
  const bf16x8 qA1 = *reinterpret_cast<const bf16x8*>(Qb + (size_t)irA * HD + quad * 8 + 32);
  const bf16x8 qB0 = *reinterpret_cast<const bf16x8*>(Qb + (size_t)irB * HD + quad * 8);
  const bf16x8 qB1 = *reinterpret_cast<const bf16x8*>(Qb + (size_t)irB * HD + quad * 8 + 32);
  const int padA = maskb[irA], padB = maskb[irB];

  f32x4 oA[4], oB[4];
#pragma unroll
  for (int vt = 0; vt < 4; ++vt) { oA[vt] = f32x4{0,0,0,0}; oB[vt] = f32x4{0,0,0,0}; }
  // init -1e20 (not -1e30): all-masked tiles then give exp2(-1e30+1e20)=0 safely
  float mA = -1e20f, lA = 0.f, mB = -1e20f, lB = 0.f;

  // staging bases: wave 0 stages K (8 calls of 8 rows), wave 1 stages V^T
  const int srowg = lane >> 3;                       // 0..7
  const int schunk = (lane & 7) ^ (srowg & 7);       // swizzled chunk
  const unsigned short* Ksrc = Kb + (size_t)srowg * HD + schunk * 8;       // + (j0+t*8)*HD
  const unsigned short* Vsrc = Vtb + (size_t)srowg * SEQ + schunk * 8;     // + t*8*SEQ + j0
  const int cA0 = (quad ^ (fr & 7)) * 8;             // frag chunk for k in [0,32)
  const int cA1 = ((quad + 4) ^ (fr & 7)) * 8;       // frag chunk for k in [32,64)

  for (int jc = 0; jc <= ibA; ++jc) {
    const int j0 = jc * 64;
    if (wave == 0) {
#pragma unroll
      for (int t = 0; t < 8; ++t)
        gl2lds16(Ksrc + (size_t)(j0 + t * 8) * HD, Ks + t * 8 * 64);
    } else {
#pragma unroll
      for (int t = 0; t < 8; ++t)
        gl2lds16(Vsrc + (size_t)(t * 8) * SEQ + j0, Vts + t * 8 * 64);
    }
    __syncthreads();  // drains vmcnt: staged tiles visible

    const bool doB = (jc <= ibB);
    const bool tb = ((bm >> (2 * jc)) & 3ull) != 0ull;

    // S^T strips for both i-tiles, sharing the Ks fragment reads
    f32x4 stA[4], stB[4];
#pragma unroll
    for (int jt = 0; jt < 4; ++jt) {
      bf16x8 ka0 = *reinterpret_cast<const bf16x8*>(&Ks[(jt * 16 + fr) * 64 + cA0]);
      bf16x8 ka1 = *reinterpret_cast<const bf16x8*>(&Ks[(jt * 16 + fr) * 64 + cA1]);
      stA[jt] = f32x4{0,0,0,0};
      stA[jt] = __builtin_amdgcn_mfma_f32_16x16x32_bf16(ka0, qA0, stA[jt], 0, 0, 0);
      stA[jt] = __builtin_amdgcn_mfma_f32_16x16x32_bf16(ka1, qA1, stA[jt], 0, 0, 0);
      if (doB) {
        stB[jt] = f32x4{0,0,0,0};
        stB[jt] = __builtin_amdgcn_mfma_f32_16x16x32_bf16(ka0, qB0, stB[jt], 0, 0, 0);
        stB[jt] = __builtin_amdgcn_mfma_f32_16x16x32_bf16(ka1, qB1, stB[jt], 0, 0, 0);
      }
    }

    if (tb) {  // rare: per-element pad-col mask
      const int4* mp = reinterpret_cast<const int4*>(maskb + j0);
#pragma unroll
      for (int jt = 0; jt < 4; ++jt) {
        const int4 mv = mp[jt * 4 + quad];
        if (mv.x == 0) { stA[jt][0] = -1e30f; if (doB) stB[jt][0] = -1e30f; }
        if (mv.y == 0) { stA[jt][1] = -1e30f; if (doB) stB[jt][1] = -1e30f; }
        if (mv.z == 0) { stA[jt][2] = -1e30f; if (doB) stB[jt][2] = -1e30f; }
        if (mv.w == 0) { stA[jt][3] = -1e30f; if (doB) stB[jt][3] = -1e30f; }
      }
    }
    if (jc == ibA) {  // causal mask, tile A
#pragma unroll
      for (int jt = 0; jt < 4; ++jt) {
        const int jb = j0 + jt * 16 + quad * 4;
#pragma unroll
        for (int r = 0; r < 4; ++r)
          if (jb + r > irA) stA[jt][r] = -1e30f;
      }
    }
    if (doB && jc == ibB) {  // causal mask, tile B
#pragma unroll
      for (int jt = 0; jt < 4; ++jt) {
        const int jb = j0 + jt * 16 + quad * 4;
#pragma unroll
        for (int r = 0; r < 4; ++r)
          if (jb + r > irB) stB[jt][r] = -1e30f;
      }
    }

    // ---- softmax + Pt pack, tile A ----
    {
      float tmax = -1e30f;
#pragma unroll
      for (int jt = 0; jt < 4; ++jt)
#pragma unroll
        for (int r = 0; r < 4; ++r) tmax = fmaxf(tmax, stA[jt][r]);
      tmax = fmaxf(tmax, __shfl_xor(tmax, 16));
      tmax = fmaxf(tmax, __shfl_xor(tmax, 32));
      const bool upd = __ballot(tmax > mA) != 0ull;  // wave-uniform
      float corr = 1.f;
      if (upd) { const float mn = fmaxf(mA, tmax); corr = __builtin_amdgcn_exp2f(mA - mn); mA = mn; }
      float lloc = 0.f;
#pragma unroll
      for (int jt = 0; jt < 4; ++jt) {
        float p0 = __builtin_amdgcn_exp2f(stA[jt][0] - mA);
        float p1 = __builtin_amdgcn_exp2f(stA[jt][1] - mA);
        float p2 = __builtin_amdgcn_exp2f(stA[jt][2] - mA);
        float p3 = __builtin_amdgcn_exp2f(stA[jt][3] - mA);
        lloc += (p0 + p1) + (p2 + p3);
        uint2 pk; pk.x = pk2bf(p0, p1); pk.y = pk2bf(p2, p3);
        *reinterpret_cast<uint2*>(&Pt[wave][0][fr][jt * 16 + quad * 4]) = pk;
      }
      lloc += __shfl_xor(lloc, 16);
      lloc += __shfl_xor(lloc, 32);
      if (upd) {
        lA = lA * corr + lloc;
#pragma unroll
        for (int vt = 0; vt < 4; ++vt) {
          oA[vt][0] *= corr; oA[vt][1] *= corr; oA[vt][2] *= corr; oA[vt][3] *= corr;
        }
      } else lA += lloc;
    }
    // ---- softmax + Pt pack, tile B ----
    if (doB) {
      float tmax = -1e30f;
#pragma unroll
      for (int jt = 0; jt < 4; ++jt)
#pragma unroll
        for (int r = 0; r < 4; ++r) tmax = fmaxf(tmax, stB[jt][r]);
      tmax = fmaxf(tmax, __shfl_xor(tmax, 16));
      tmax = fmaxf(tmax, __shfl_xor(tmax, 32));
      const bool upd = __ballot(tmax > mB) != 0ull;
      float corr = 1.f;
      if (upd) { const float mn = fmaxf(mB, tmax); corr = __builtin_amdgcn_exp2f(mB - mn); mB = mn; }
      float lloc = 0.f;
#pragma unroll
      for (int jt = 0; jt < 4; ++jt) {
        float p0 = __builtin_amdgcn_exp2f(stB[jt][0] - mB);
        float p1 = __builtin_amdgcn_exp2f(stB[jt][1] - mB);
        float p2 = __builtin_amdgcn_exp2f(stB[jt][2] - mB);
        float p3 = __builtin_amdgcn_exp2f(stB[jt][3] - mB);
        lloc += (p0 + p1) + (p2 + p3);
        uint2 pk; pk.x = pk2bf(p0, p1); pk.y = pk2bf(p2, p3);
        *reinterpret_cast<uint2*>(&Pt[wave][1][fr][jt * 16 + quad * 4]) = pk;
      }
      lloc += __shfl_xor(lloc, 16);
      lloc += __shfl_xor(lloc, 32);
      if (upd) {
        lB = lB * corr + lloc;
#pragma unroll
        for (int vt = 0; vt < 4; ++vt) {
          oB[vt][0] *= corr; oB[vt][1] *= corr; oB[vt][2] *= corr; oB[vt][3] *= corr;
        }
      } else lB += lloc;
    }

    // ---- O^T += V^T * P^T, sharing Vts fragment reads ----
    bf16x8 paA0 = *reinterpret_cast<const bf16x8*>(&Pt[wave][0][fr][quad * 8]);
    bf16x8 paA1 = *reinterpret_cast<const bf16x8*>(&Pt[wave][0][fr][quad * 8 + 32]);
    bf16x8 paB0, paB1;
    if (doB) {
      paB0 = *reinterpret_cast<const bf16x8*>(&Pt[wave][1][fr][quad * 8]);
      paB1 = *reinterpret_cast<const bf16x8*>(&Pt[wave][1][fr][quad * 8 + 32]);
    }
#pragma unroll
    for (int vt = 0; vt < 4; ++vt) {
      bf16x8 vb0 = *reinterpret_cast<const bf16x8*>(&Vts[(vt * 16 + fr) * 64 + cA0]);
      bf16x8 vb1 = *reinterpret_cast<const bf16x8*>(&Vts[(vt * 16 + fr) * 64 + cA1]);
      oA[vt] = __builtin_amdgcn_mfma_f32_16x16x32_bf16(vb0, paA0, oA[vt], 0, 0, 0);
      oA[vt] = __builtin_amdgcn_mfma_f32_16x16x32_bf16(vb1, paA1, oA[vt], 0, 0, 0);
      if (doB) {
        oB[vt] = __builtin_amdgcn_mfma_f32_16x16x32_bf16(vb0, paB0, oB[vt], 0, 0, 0);
        oB[vt] = __builtin_amdgcn_mfma_f32_16x16x32_bf16(vb1, paB1, oB[vt], 0, 0, 0);
      }
    }
    __syncthreads();  // protect Ks/Vts before next stage
  }

  // epilogue: O^T[v][i=fr] / l_i -> concat bf16 [b,s,h*64]
  {
    const float inv = (padA != 0 && lA > 0.f) ? 1.f / lA : 0.f;
    unsigned short* orow = concat + ((size_t)(b * SEQ + irA)) * DMODEL + h * HD;
#pragma unroll
    for (int vt = 0; vt < 4; ++vt) {
      uint2 pk;
      pk.x = pk2bf(oA[vt][0] * inv, oA[vt][1] * inv);
      pk.y = pk2bf(oA[vt][2] * inv, oA[vt][3] * inv);
      *reinterpret_cast<uint2*>(orow + vt * 16 + quad * 4) = pk;
    }
  }
  {
    const float inv = (padB != 0 && lB > 0.f) ? 1.f / lB : 0.f;
    unsigned short* orow = concat + ((size_t)(b * SEQ + irB)) * DMODEL + h * HD;
#pragma unroll
    for (int vt = 0; vt < 4; ++vt) {
      uint2 pk;
      pk.x = pk2bf(oB[vt][0] * inv, oB[vt][1] * inv);
      pk.y = pk2bf(oB[vt][2] * inv, oB[vt][3] * inv);
      *reinterpret_cast<uint2*>(orow + vt * 16 + quad * 4) = pk;
    }
  }
}

extern "C" void kernel_launch(void* const* d_in, const int* in_sizes, int n_in,
                              void* d_out, int out_size, void* d_ws, size_t ws_size,
                              hipStream_t stream) {
  (void)in_sizes; (void)n_in; (void)out_size;
  const float* x  = (const float*)d_in[0];
  const int* mask = (const int*)d_in[1];
  const float* Wq = (const float*)d_in[2];
  const float* bq = (const float*)d_in[3];
  const float* Wk = (const float*)d_in[4];
  const float* bk = (const float*)d_in[5];
  const float* Wv = (const float*)d_in[6];
  const float* bv = (const float*)d_in[7];
  const float* Wo = (const float*)d_in[8];
  const float* bo = (const float*)d_in[9];
  float* out = (float*)d_out;

  char* ws = (char*)d_ws;
  if (ws_size < (48ull << 20)) return;
  unsigned short* xb  = (unsigned short*)(ws);                 // 8 MB x bf16 [4096][1024]
  unsigned short* wqb = (unsigned short*)(ws + (8ull  << 20)); // wq|wk|wv contiguous ->
  unsigned short* wkb = (unsigned short*)(ws + (10ull << 20)); //   [3072][1024] B matrix
  unsigned short* wvb = (unsigned short*)(ws + (12ull << 20));
  unsigned short* wob = (unsigned short*)(ws + (14ull << 20));
  unsigned short* Qb  = (unsigned short*)(ws + (16ull << 20)); // 8 MB [b,h,s,64] (xscale)
  unsigned short* Kb  = (unsigned short*)(ws + (24ull << 20)); // 8 MB [b,h,s,64]
  unsigned short* Vtb = (unsigned short*)(ws + (32ull << 20)); // 8 MB [b,h,64,s]
  unsigned short* cb  = (unsigned short*)(ws + (40ull << 20)); // 8 MB concat bf16

  cast_all_kernel<<<4096, 256, 0, stream>>>(x, Wq, Wk, Wv, Wo, xb, wqb, wkb, wvb, wob);

  // fused QKV projection: B = [wq; wk; wv] = [3072][1024]
  gemm128<0><<<dim3(24, 32), 256, 0, stream>>>(xb, wqb, bq, bk, bv,
                                               nullptr, Qb, Kb, Vtb, 1024);

  attn_mfma_kernel<<<1024, 128, 0, stream>>>(Qb, Kb, Vtb, mask, cb);

  gemm128<1><<<dim3(8, 32), 256, 0, stream>>>(cb, wob, bo, nullptr, nullptr,
                                              out, nullptr, nullptr, nullptr, 1024);
}